// Round 3
// baseline (918.372 us; speedup 1.0000x reference)
//
#include <hip/hip_runtime.h>
#include <hip/hip_bf16.h>
#include <math.h>

#define T_TOK 8192
#define DMODEL 1024
#define FFN 4096
#define NEXP 8
#define NSLOT (T_TOK * 2)
#define MAXT 72  // sum ceil(c_e/256) <= 64+8 = 72

typedef _Float16 f16;
typedef _Float16 half8 __attribute__((ext_vector_type(8)));
typedef float f32x4 __attribute__((ext_vector_type(4)));
typedef unsigned int u32;

__device__ __forceinline__ void gll16(const void* g, void* l) {
  __builtin_amdgcn_global_load_lds(
      (const __attribute__((address_space(1))) u32*)g,
      (__attribute__((address_space(3))) u32*)l, 16, 0, 0);
}

__device__ __forceinline__ float gelu_exact(float v) {
  return 0.5f * v * (1.0f + erff(v * 0.70710678118654752f));
}

// ---------------- router ---------------------------------------------------
__global__ __launch_bounds__(256) void router_k(
    const float* __restrict__ x, const float* __restrict__ Wr,
    int* __restrict__ sel_e, float* __restrict__ sel_w, int* __restrict__ counts) {
  int t = blockIdx.x * 4 + (threadIdx.x >> 6);
  int lane = threadIdx.x & 63;
  const float* xp = x + (size_t)t * DMODEL;
  float p[NEXP];
#pragma unroll
  for (int e = 0; e < NEXP; e++) p[e] = 0.f;
#pragma unroll
  for (int i = 0; i < DMODEL / 64; i++) {
    float xv = xp[lane + i * 64];
#pragma unroll
    for (int e = 0; e < NEXP; e++) p[e] += xv * Wr[e * DMODEL + lane + i * 64];
  }
#pragma unroll
  for (int off = 32; off; off >>= 1) {
#pragma unroll
    for (int e = 0; e < NEXP; e++) p[e] += __shfl_xor(p[e], off);
  }
  if (lane == 0) {
    float l0 = -1e30f, l1 = -1e30f;
    int e0 = 0, e1 = 1;
#pragma unroll
    for (int e = 0; e < NEXP; e++) {
      if (p[e] > l0) { l1 = l0; e1 = e0; l0 = p[e]; e0 = e; }
      else if (p[e] > l1) { l1 = p[e]; e1 = e; }
    }
    float r = expf(l1 - l0);
    float inv = 1.f / (1.f + r);
    sel_e[t * 2] = e0;     sel_w[t * 2] = inv;
    sel_e[t * 2 + 1] = e1; sel_w[t * 2 + 1] = r * inv;
    atomicAdd(&counts[e0], 1);
    atomicAdd(&counts[e1], 1);
  }
}

// ---------------- schedule (256-row tiles) ---------------------------------
__global__ void sched_k(int* meta) {
  int* counts = meta;
  int* fill = meta + 64;
  int* offs = meta + 128;
  int* tE = meta + 256;
  int* tR0 = meta + 512;
  int* tRows = meta + 768;
  int off = 0, nt = 0;
  for (int e = 0; e < NEXP; e++) {
    offs[e] = off;
    fill[e] = 0;
    int c = counts[e];
    for (int t0 = 0; t0 < c; t0 += 256) {
      tE[nt] = e; tR0[nt] = off + t0; tRows[nt] = min(256, c - t0); nt++;
    }
    off += c;
  }
  offs[NEXP] = off;
  for (; nt < MAXT; nt++) tE[nt] = -1;
}

// ---------------- scatter --------------------------------------------------
__global__ __launch_bounds__(256) void scatter_k(
    const int* __restrict__ sel_e, const float* __restrict__ sel_w,
    const int* __restrict__ offs, int* fill,
    int* __restrict__ row_tok, float* __restrict__ row_w) {
  int s = blockIdx.x * 256 + threadIdx.x;
  int e = sel_e[s];
  int pos = atomicAdd(&fill[e], 1);
  int r = offs[e] + pos;
  row_tok[r] = s >> 1;
  row_w[r] = sel_w[s];
}

// ---------------- f32 -> f16 elementwise (x) -------------------------------
__global__ __launch_bounds__(256) void cvtx_k(const float* __restrict__ x,
                                              f16* __restrict__ xh) {
  int i = blockIdx.x * 256 + threadIdx.x;
  const float4* src = (const float4*)x;
  float4 a = src[i * 2], b = src[i * 2 + 1];
  half8 h;
  h[0] = (f16)a.x; h[1] = (f16)a.y; h[2] = (f16)a.z; h[3] = (f16)a.w;
  h[4] = (f16)b.x; h[5] = (f16)b.y; h[6] = (f16)b.z; h[7] = (f16)b.w;
  ((half8*)xh)[i] = h;
}

// ------------- transpose+convert 64x64: out[e][c][r] = (f16) in[e][r][c] ---
__global__ __launch_bounds__(256) void transq_k(const float* __restrict__ in,
                                                f16* __restrict__ out, int R, int C) {
  __shared__ float tile[64][69];
  int e = blockIdx.z;
  const float* ip = in + (size_t)e * R * C;
  f16* op = out + (size_t)e * R * C;
  int c0 = blockIdx.x * 64, r0 = blockIdx.y * 64;
  int tx = threadIdx.x & 15, ty = threadIdx.x >> 4;
#pragma unroll
  for (int rr = 0; rr < 4; rr++) {
    float4 v = *(const float4*)(ip + (size_t)(r0 + ty + rr * 16) * C + c0 + tx * 4);
    int r = ty + rr * 16;
    tile[r][tx * 4 + 0] = v.x; tile[r][tx * 4 + 1] = v.y;
    tile[r][tx * 4 + 2] = v.z; tile[r][tx * 4 + 3] = v.w;
  }
  __syncthreads();
  int ch = threadIdx.x & 7, cc = threadIdx.x >> 3;
#pragma unroll
  for (int pp = 0; pp < 2; pp++) {
    int c = cc + pp * 32;
    half8 h;
#pragma unroll
    for (int i = 0; i < 8; i++) h[i] = (f16)tile[ch * 8 + i][c];
    *(half8*)(op + (size_t)(c0 + c) * R + r0 + ch * 8) = h;
  }
}

// ============ GEMM1: H = gelu(Xg @ W_in + b_in), 256x256xBK64 ==============
__global__ __launch_bounds__(512, 1) void gemm1_k(
    const f16* __restrict__ Xh, const f16* __restrict__ Wt,
    const float* __restrict__ b_in, f16* __restrict__ H,
    const int* __restrict__ meta) {
  int G = gridDim.x;
  int wg = ((blockIdx.x & 7) * (G >> 3)) + (blockIdx.x >> 3);
  int tm = wg >> 4;            // tm-slow: 16 consecutive wg share A panel in L2
  int n0 = (wg & 15) * 256;
  int e = (meta + 256)[tm];
  if (e < 0) return;
  int row0 = (meta + 512)[tm];
  int nrows = (meta + 768)[tm];
  const int* row_tok = meta + 1024 + 2 * NSLOT;

  __shared__ __align__(16) char smem[135168];  // 128K staging + 135168 epilogue union

  int tid = threadIdx.x, lane = tid & 63, wid = tid >> 6;
  int wrow = wid >> 2, wcol = wid & 3;
  int l15 = lane & 15, l4 = lane >> 4;

  u32 aoff[4], boff[4];
#pragma unroll
  for (int p = 0; p < 4; p++) {
    int L = tid + p * 512;
    int row = L >> 3, ch = L & 7;
    int cs = ch ^ (row & 7);                       // pre-swizzled source chunk
    int rg = min(row0 + row, NSLOT - 1);
    aoff[p] = (u32)((row_tok[rg] * DMODEL + cs * 8) * 2);
    boff[p] = (u32)(((u32)(e * FFN + n0 + row) * DMODEL + cs * 8) * 2);
  }
  const char* gA = (const char*)Xh;
  const char* gB = (const char*)Wt;

  f32x4 acc[8][4];
#pragma unroll
  for (int m = 0; m < 8; m++)
#pragma unroll
    for (int n = 0; n < 4; n++) acc[m][n] = (f32x4)0.f;

#pragma unroll
  for (int p = 0; p < 4; p++) {                    // prologue: kt0 -> buf0
    gll16(gA + aoff[p], smem + (tid + p * 512) * 16);
    gll16(gB + boff[p], smem + 65536 + (tid + p * 512) * 16);
    aoff[p] += 128; boff[p] += 128;
  }
  asm volatile("s_waitcnt vmcnt(0)" ::: "memory");
  __builtin_amdgcn_s_barrier();

  const int NT = DMODEL / 64;  // 16
  half8 a[4][2], b0[2][2], b1[2][2];

  for (int kt = 0; kt < NT; ++kt) {
    int d = kt & 1, dn = d ^ 1;
    const char* cA = smem + d * 32768;
    const char* cB = smem + 65536 + d * 32768;
    // phase 0 (m0,n0): read A0(8)+B0(4), stage 8
#pragma unroll
    for (int i = 0; i < 4; i++)
#pragma unroll
      for (int s = 0; s < 2; s++) {
        int r = wrow * 128 + i * 16 + l15, c = s * 4 + l4;
        a[i][s] = *(const half8*)(cA + r * 128 + ((c ^ (r & 7)) << 4));
      }
#pragma unroll
    for (int j = 0; j < 2; j++)
#pragma unroll
      for (int s = 0; s < 2; s++) {
        int r = wcol * 64 + j * 16 + l15, c = s * 4 + l4;
        b0[j][s] = *(const half8*)(cB + r * 128 + ((c ^ (r & 7)) << 4));
      }
#pragma unroll
    for (int p = 0; p < 4; p++) {
      gll16(gA + aoff[p], smem + dn * 32768 + (tid + p * 512) * 16);
      gll16(gB + boff[p], smem + 65536 + dn * 32768 + (tid + p * 512) * 16);
      aoff[p] += 128; boff[p] += 128;
    }
    __builtin_amdgcn_s_barrier();
    asm volatile("s_waitcnt lgkmcnt(0)" ::: "memory");
    __builtin_amdgcn_sched_barrier(0);
    __builtin_amdgcn_s_setprio(1);
#pragma unroll
    for (int i = 0; i < 4; i++)
#pragma unroll
      for (int j = 0; j < 2; j++)
#pragma unroll
        for (int s = 0; s < 2; s++)
          acc[i][j] = __builtin_amdgcn_mfma_f32_16x16x32_f16(a[i][s], b0[j][s], acc[i][j], 0, 0, 0);
    __builtin_amdgcn_s_setprio(0);
    __builtin_amdgcn_s_barrier();
    // phase 1 (m0,n1): read B1(4)
#pragma unroll
    for (int j = 0; j < 2; j++)
#pragma unroll
      for (int s = 0; s < 2; s++) {
        int r = wcol * 64 + (2 + j) * 16 + l15, c = s * 4 + l4;
        b1[j][s] = *(const half8*)(cB + r * 128 + ((c ^ (r & 7)) << 4));
      }
    __builtin_amdgcn_s_barrier();
    asm volatile("s_waitcnt lgkmcnt(0)" ::: "memory");
    __builtin_amdgcn_sched_barrier(0);
    __builtin_amdgcn_s_setprio(1);
#pragma unroll
    for (int i = 0; i < 4; i++)
#pragma unroll
      for (int j = 0; j < 2; j++)
#pragma unroll
        for (int s = 0; s < 2; s++)
          acc[i][2 + j] = __builtin_amdgcn_mfma_f32_16x16x32_f16(a[i][s], b1[j][s], acc[i][2 + j], 0, 0, 0);
    __builtin_amdgcn_s_setprio(0);
    __builtin_amdgcn_s_barrier();
    // phase 2 (m1,n0): read A1(8)
#pragma unroll
    for (int i = 0; i < 4; i++)
#pragma unroll
      for (int s = 0; s < 2; s++) {
        int r = wrow * 128 + (4 + i) * 16 + l15, c = s * 4 + l4;
        a[i][s] = *(const half8*)(cA + r * 128 + ((c ^ (r & 7)) << 4));
      }
    __builtin_amdgcn_s_barrier();
    asm volatile("s_waitcnt lgkmcnt(0)" ::: "memory");
    __builtin_amdgcn_sched_barrier(0);
    __builtin_amdgcn_s_setprio(1);
#pragma unroll
    for (int i = 0; i < 4; i++)
#pragma unroll
      for (int j = 0; j < 2; j++)
#pragma unroll
        for (int s = 0; s < 2; s++)
          acc[4 + i][j] = __builtin_amdgcn_mfma_f32_16x16x32_f16(a[i][s], b0[j][s], acc[4 + i][j], 0, 0, 0);
    __builtin_amdgcn_s_setprio(0);
    __builtin_amdgcn_s_barrier();
    // phase 3 (m1,n1): no reads; drain vmem before final barrier
    __builtin_amdgcn_s_setprio(1);
#pragma unroll
    for (int i = 0; i < 4; i++)
#pragma unroll
      for (int j = 0; j < 2; j++)
#pragma unroll
        for (int s = 0; s < 2; s++)
          acc[4 + i][2 + j] = __builtin_amdgcn_mfma_f32_16x16x32_f16(a[i][s], b1[j][s], acc[4 + i][2 + j], 0, 0, 0);
    __builtin_amdgcn_s_setprio(0);
    asm volatile("s_waitcnt vmcnt(0)" ::: "memory");
    __builtin_amdgcn_s_barrier();
  }

  // epilogue: bias+gelu -> f16 LDS repack [256][264] -> float4 stores
  float bias[4];
#pragma unroll
  for (int n = 0; n < 4; n++) bias[n] = b_in[e * FFN + n0 + wcol * 64 + n * 16 + l15];
#pragma unroll
  for (int m = 0; m < 8; m++)
#pragma unroll
    for (int n = 0; n < 4; n++)
#pragma unroll
      for (int j = 0; j < 4; j++) {
        int row = wrow * 128 + m * 16 + l4 * 4 + j;
        int col = wcol * 64 + n * 16 + l15;
        *(f16*)(smem + row * 528 + col * 2) = (f16)gelu_exact(acc[m][n][j] + bias[n]);
      }
  __syncthreads();
#pragma unroll
  for (int p = 0; p < 16; ++p) {
    int idx = tid + p * 512;
    int row = idx >> 5, cc = idx & 31;
    if (row < nrows)
      *(float4*)(H + (size_t)(row0 + row) * FFN + n0 + cc * 8) =
          *(const float4*)(smem + row * 528 + cc * 16);
  }
}

// ============ GEMM2: out[tok] += w * (H @ W_out + b_out), 256x256xBK64 =====
__global__ __launch_bounds__(512, 1) void gemm2_k(
    const f16* __restrict__ H, const f16* __restrict__ Wt,
    const float* __restrict__ b_out, float* __restrict__ out,
    const int* __restrict__ meta) {
  int G = gridDim.x;
  int wg = ((blockIdx.x & 7) * (G >> 3)) + (blockIdx.x >> 3);
  int tm = wg >> 2;            // tm-slow: 4 consecutive wg share A panel
  int n0 = (wg & 3) * 256;
  int e = (meta + 256)[tm];
  if (e < 0) return;
  int row0 = (meta + 512)[tm];
  int nrows = (meta + 768)[tm];
  const int* row_tok = meta + 1024 + 2 * NSLOT;
  const float* row_w = (const float*)(meta + 1024 + 3 * NSLOT);

  __shared__ __align__(16) char smem[131072];

  int tid = threadIdx.x, lane = tid & 63, wid = tid >> 6;
  int wrow = wid >> 2, wcol = wid & 3;
  int l15 = lane & 15, l4 = lane >> 4;

  u32 aoff[4], boff[4];
#pragma unroll
  for (int p = 0; p < 4; p++) {
    int L = tid + p * 512;
    int row = L >> 3, ch = L & 7;
    int cs = ch ^ (row & 7);
    u32 rg = (u32)min(row0 + row, NSLOT - 1);
    aoff[p] = (u32)((rg * FFN + cs * 8) * 2);
    boff[p] = (u32)(((u32)(e * DMODEL + n0 + row) * FFN + cs * 8) * 2);
  }
  const char* gA = (const char*)H;
  const char* gB = (const char*)Wt;

  f32x4 acc[8][4];
#pragma unroll
  for (int m = 0; m < 8; m++)
#pragma unroll
    for (int n = 0; n < 4; n++) acc[m][n] = (f32x4)0.f;

#pragma unroll
  for (int p = 0; p < 4; p++) {
    gll16(gA + aoff[p], smem + (tid + p * 512) * 16);
    gll16(gB + boff[p], smem + 65536 + (tid + p * 512) * 16);
    aoff[p] += 128; boff[p] += 128;
  }
  asm volatile("s_waitcnt vmcnt(0)" ::: "memory");
  __builtin_amdgcn_s_barrier();

  const int NT = FFN / 64;  // 64
  half8 a[4][2], b0[2][2], b1[2][2];

  for (int kt = 0; kt < NT; ++kt) {
    int d = kt & 1, dn = d ^ 1;
    const char* cA = smem + d * 32768;
    const char* cB = smem + 65536 + d * 32768;
#pragma unroll
    for (int i = 0; i < 4; i++)
#pragma unroll
      for (int s = 0; s < 2; s++) {
        int r = wrow * 128 + i * 16 + l15, c = s * 4 + l4;
        a[i][s] = *(const half8*)(cA + r * 128 + ((c ^ (r & 7)) << 4));
      }
#pragma unroll
    for (int j = 0; j < 2; j++)
#pragma unroll
      for (int s = 0; s < 2; s++) {
        int r = wcol * 64 + j * 16 + l15, c = s * 4 + l4;
        b0[j][s] = *(const half8*)(cB + r * 128 + ((c ^ (r & 7)) << 4));
      }
#pragma unroll
    for (int p = 0; p < 4; p++) {
      gll16(gA + aoff[p], smem + dn * 32768 + (tid + p * 512) * 16);
      gll16(gB + boff[p], smem + 65536 + dn * 32768 + (tid + p * 512) * 16);
      aoff[p] += 128; boff[p] += 128;
    }
    __builtin_amdgcn_s_barrier();
    asm volatile("s_waitcnt lgkmcnt(0)" ::: "memory");
    __builtin_amdgcn_sched_barrier(0);
    __builtin_amdgcn_s_setprio(1);
#pragma unroll
    for (int i = 0; i < 4; i++)
#pragma unroll
      for (int j = 0; j < 2; j++)
#pragma unroll
        for (int s = 0; s < 2; s++)
          acc[i][j] = __builtin_amdgcn_mfma_f32_16x16x32_f16(a[i][s], b0[j][s], acc[i][j], 0, 0, 0);
    __builtin_amdgcn_s_setprio(0);
    __builtin_amdgcn_s_barrier();
#pragma unroll
    for (int j = 0; j < 2; j++)
#pragma unroll
      for (int s = 0; s < 2; s++) {
        int r = wcol * 64 + (2 + j) * 16 + l15, c = s * 4 + l4;
        b1[j][s] = *(const half8*)(cB + r * 128 + ((c ^ (r & 7)) << 4));
      }
    __builtin_amdgcn_s_barrier();
    asm volatile("s_waitcnt lgkmcnt(0)" ::: "memory");
    __builtin_amdgcn_sched_barrier(0);
    __builtin_amdgcn_s_setprio(1);
#pragma unroll
    for (int i = 0; i < 4; i++)
#pragma unroll
      for (int j = 0; j < 2; j++)
#pragma unroll
        for (int s = 0; s < 2; s++)
          acc[i][2 + j] = __builtin_amdgcn_mfma_f32_16x16x32_f16(a[i][s], b1[j][s], acc[i][2 + j], 0, 0, 0);
    __builtin_amdgcn_s_setprio(0);
    __builtin_amdgcn_s_barrier();
#pragma unroll
    for (int i = 0; i < 4; i++)
#pragma unroll
      for (int s = 0; s < 2; s++) {
        int r = wrow * 128 + (4 + i) * 16 + l15, c = s * 4 + l4;
        a[i][s] = *(const half8*)(cA + r * 128 + ((c ^ (r & 7)) << 4));
      }
    __builtin_amdgcn_s_barrier();
    asm volatile("s_waitcnt lgkmcnt(0)" ::: "memory");
    __builtin_amdgcn_sched_barrier(0);
    __builtin_amdgcn_s_setprio(1);
#pragma unroll
    for (int i = 0; i < 4; i++)
#pragma unroll
      for (int j = 0; j < 2; j++)
#pragma unroll
        for (int s = 0; s < 2; s++)
          acc[4 + i][j] = __builtin_amdgcn_mfma_f32_16x16x32_f16(a[i][s], b0[j][s], acc[4 + i][j], 0, 0, 0);
    __builtin_amdgcn_s_setprio(0);
    __builtin_amdgcn_s_barrier();
    __builtin_amdgcn_s_setprio(1);
#pragma unroll
    for (int i = 0; i < 4; i++)
#pragma unroll
      for (int j = 0; j < 2; j++)
#pragma unroll
        for (int s = 0; s < 2; s++)
          acc[4 + i][2 + j] = __builtin_amdgcn_mfma_f32_16x16x32_f16(a[i][s], b1[j][s], acc[4 + i][2 + j], 0, 0, 0);
    __builtin_amdgcn_s_setprio(0);
    asm volatile("s_waitcnt vmcnt(0)" ::: "memory");
    __builtin_amdgcn_s_barrier();
  }

  float bias[4];
#pragma unroll
  for (int n = 0; n < 4; n++) bias[n] = b_out[e * DMODEL + n0 + wcol * 64 + n * 16 + l15];
#pragma unroll
  for (int m = 0; m < 8; m++)
#pragma unroll
    for (int j = 0; j < 4; j++) {
      int r = wrow * 128 + m * 16 + l4 * 4 + j;
      if (r < nrows) {
        int rg = row0 + r;
        int tok = row_tok[rg];
        float w = row_w[rg];
#pragma unroll
        for (int n = 0; n < 4; n++)
          atomicAdd(out + (size_t)tok * DMODEL + n0 + wcol * 64 + n * 16 + l15,
                    w * (acc[m][n][j] + bias[n]));
      }
    }
}

// ---------------- fallback (small workspace) -------------------------------
__global__ __launch_bounds__(256) void naive_k(
    const float* __restrict__ x, const float* __restrict__ W_in,
    const float* __restrict__ b_in, const float* __restrict__ W_out,
    const float* __restrict__ b_out, const int* __restrict__ sel_e,
    const float* __restrict__ sel_w, float* __restrict__ out) {
  int s = blockIdx.x;
  int t = s >> 1;
  int e = sel_e[s];
  float w = sel_w[s];
  __shared__ float xs[DMODEL];
  __shared__ float hs[FFN];
  int tid = threadIdx.x;
  for (int d = tid; d < DMODEL; d += 256) xs[d] = x[(size_t)t * DMODEL + d];
  __syncthreads();
  for (int f = tid; f < FFN; f += 256) {
    float a = b_in[e * FFN + f];
    const float* wp = W_in + (size_t)e * DMODEL * FFN + f;
    for (int d = 0; d < DMODEL; d++) a += xs[d] * wp[(size_t)d * FFN];
    hs[f] = gelu_exact(a);
  }
  __syncthreads();
  for (int d = tid; d < DMODEL; d += 256) {
    float a = b_out[e * DMODEL + d];
    const float* wp = W_out + (size_t)e * FFN * DMODEL + d;
    for (int f = 0; f < FFN; f++) a += hs[f] * wp[(size_t)f * DMODEL];
    atomicAdd(&out[(size_t)t * DMODEL + d], w * a);
  }
}

extern "C" void kernel_launch(void* const* d_in, const int* in_sizes, int n_in,
                              void* d_out, int out_size, void* d_ws, size_t ws_size,
                              hipStream_t stream) {
  const float* residual = (const float*)d_in[0];
  const float* W_router = (const float*)d_in[1];
  const float* W_in = (const float*)d_in[2];
  const float* b_in = (const float*)d_in[3];
  const float* W_out = (const float*)d_in[4];
  const float* b_out = (const float*)d_in[5];
  float* out = (float*)d_out;

  char* ws = (char*)d_ws;
  int* meta = (int*)ws;
  size_t off = (size_t)1 << 20;
  f16* Xh = (f16*)(ws + off); off += (size_t)T_TOK * DMODEL * 2;       // 16 MB
  f16* Wih = (f16*)(ws + off); off += (size_t)NEXP * DMODEL * FFN * 2; // 64 MB
  f16* Woh = (f16*)(ws + off); off += (size_t)NEXP * DMODEL * FFN * 2; // 64 MB
  f16* H = (f16*)(ws + off); off += (size_t)NSLOT * FFN * 2;           // 128 MB
  off += 65536;                                                        // OOB-read slack
  bool fast = ws_size >= off;

  int* sel_e = meta + 1024;
  float* sel_w = (float*)(meta + 1024 + NSLOT);
  int* row_tok = meta + 1024 + 2 * NSLOT;
  float* row_w = (float*)(meta + 1024 + 3 * NSLOT);

  hipMemsetAsync(meta, 0, 4096, stream);
  hipMemsetAsync(d_out, 0, (size_t)out_size * sizeof(float), stream);

  router_k<<<T_TOK / 4, 256, 0, stream>>>(residual, W_router, sel_e, sel_w, meta);

  if (fast) {
    cvtx_k<<<(T_TOK * DMODEL / 8) / 256, 256, 0, stream>>>(residual, Xh);
    transq_k<<<dim3(FFN / 64, DMODEL / 64, NEXP), 256, 0, stream>>>(W_in, Wih, DMODEL, FFN);
    transq_k<<<dim3(DMODEL / 64, FFN / 64, NEXP), 256, 0, stream>>>(W_out, Woh, FFN, DMODEL);
    sched_k<<<1, 1, 0, stream>>>(meta);
    scatter_k<<<NSLOT / 256, 256, 0, stream>>>(sel_e, sel_w, meta + 128, meta + 64,
                                               row_tok, row_w);
    gemm1_k<<<MAXT * 16, 512, 0, stream>>>(Xh, Wih, b_in, H, meta);
    gemm2_k<<<MAXT * 4, 512, 0, stream>>>(H, Woh, b_out, out, meta);
  } else {
    naive_k<<<NSLOT, 256, 0, stream>>>(residual, W_in, b_in, W_out, b_out,
                                       sel_e, sel_w, out);
  }
}

// Round 4
// 903.881 us; speedup vs baseline: 1.0160x; 1.0160x over previous
//
#include <hip/hip_runtime.h>
#include <hip/hip_bf16.h>
#include <math.h>

#define T_TOK 8192
#define DMODEL 1024
#define FFN 4096
#define NEXP 8
#define NSLOT (T_TOK * 2)
#define MAXT 72  // sum ceil(c_e/256) <= 64+8 = 72

typedef _Float16 f16;
typedef _Float16 half8 __attribute__((ext_vector_type(8)));
typedef float f32x4 __attribute__((ext_vector_type(4)));
typedef unsigned int u32;

__device__ __forceinline__ void gll16(const void* g, void* l) {
  __builtin_amdgcn_global_load_lds(
      (const __attribute__((address_space(1))) u32*)g,
      (__attribute__((address_space(3))) u32*)l, 16, 0, 0);
}

__device__ __forceinline__ float gelu_exact(float v) {
  return 0.5f * v * (1.0f + erff(v * 0.70710678118654752f));
}

// ---------------- router ---------------------------------------------------
__global__ __launch_bounds__(256) void router_k(
    const float* __restrict__ x, const float* __restrict__ Wr,
    int* __restrict__ sel_e, float* __restrict__ sel_w, int* __restrict__ counts) {
  int t = blockIdx.x * 4 + (threadIdx.x >> 6);
  int lane = threadIdx.x & 63;
  const float* xp = x + (size_t)t * DMODEL;
  float p[NEXP];
#pragma unroll
  for (int e = 0; e < NEXP; e++) p[e] = 0.f;
#pragma unroll
  for (int i = 0; i < DMODEL / 64; i++) {
    float xv = xp[lane + i * 64];
#pragma unroll
    for (int e = 0; e < NEXP; e++) p[e] += xv * Wr[e * DMODEL + lane + i * 64];
  }
#pragma unroll
  for (int off = 32; off; off >>= 1) {
#pragma unroll
    for (int e = 0; e < NEXP; e++) p[e] += __shfl_xor(p[e], off);
  }
  if (lane == 0) {
    float l0 = -1e30f, l1 = -1e30f;
    int e0 = 0, e1 = 1;
#pragma unroll
    for (int e = 0; e < NEXP; e++) {
      if (p[e] > l0) { l1 = l0; e1 = e0; l0 = p[e]; e0 = e; }
      else if (p[e] > l1) { l1 = p[e]; e1 = e; }
    }
    float r = expf(l1 - l0);
    float inv = 1.f / (1.f + r);
    sel_e[t * 2] = e0;     sel_w[t * 2] = inv;
    sel_e[t * 2 + 1] = e1; sel_w[t * 2 + 1] = r * inv;
    atomicAdd(&counts[e0], 1);
    atomicAdd(&counts[e1], 1);
  }
}

// ---------------- schedule (256-row tiles) ---------------------------------
__global__ void sched_k(int* meta) {
  int* counts = meta;
  int* fill = meta + 64;
  int* offs = meta + 128;
  int* tE = meta + 256;
  int* tR0 = meta + 512;
  int* tRows = meta + 768;
  int off = 0, nt = 0;
  for (int e = 0; e < NEXP; e++) {
    offs[e] = off;
    fill[e] = 0;
    int c = counts[e];
    for (int t0 = 0; t0 < c; t0 += 256) {
      tE[nt] = e; tR0[nt] = off + t0; tRows[nt] = min(256, c - t0); nt++;
    }
    off += c;
  }
  offs[NEXP] = off;
  for (; nt < MAXT; nt++) tE[nt] = -1;
}

// ---------------- scatter --------------------------------------------------
__global__ __launch_bounds__(256) void scatter_k(
    const int* __restrict__ sel_e, const float* __restrict__ sel_w,
    const int* __restrict__ offs, int* fill,
    int* __restrict__ row_tok, float* __restrict__ row_w) {
  int s = blockIdx.x * 256 + threadIdx.x;
  int e = sel_e[s];
  int pos = atomicAdd(&fill[e], 1);
  int r = offs[e] + pos;
  row_tok[r] = s >> 1;
  row_w[r] = sel_w[s];
}

// ---------------- f32 -> f16 elementwise (x) -------------------------------
__global__ __launch_bounds__(256) void cvtx_k(const float* __restrict__ x,
                                              f16* __restrict__ xh) {
  int i = blockIdx.x * 256 + threadIdx.x;
  const float4* src = (const float4*)x;
  float4 a = src[i * 2], b = src[i * 2 + 1];
  half8 h;
  h[0] = (f16)a.x; h[1] = (f16)a.y; h[2] = (f16)a.z; h[3] = (f16)a.w;
  h[4] = (f16)b.x; h[5] = (f16)b.y; h[6] = (f16)b.z; h[7] = (f16)b.w;
  ((half8*)xh)[i] = h;
}

// ------------- transpose+convert 64x64: out[e][c][r] = (f16) in[e][r][c] ---
__global__ __launch_bounds__(256) void transq_k(const float* __restrict__ in,
                                                f16* __restrict__ out, int R, int C) {
  __shared__ float tile[64][69];
  int e = blockIdx.z;
  const float* ip = in + (size_t)e * R * C;
  f16* op = out + (size_t)e * R * C;
  int c0 = blockIdx.x * 64, r0 = blockIdx.y * 64;
  int tx = threadIdx.x & 15, ty = threadIdx.x >> 4;
#pragma unroll
  for (int rr = 0; rr < 4; rr++) {
    float4 v = *(const float4*)(ip + (size_t)(r0 + ty + rr * 16) * C + c0 + tx * 4);
    int r = ty + rr * 16;
    tile[r][tx * 4 + 0] = v.x; tile[r][tx * 4 + 1] = v.y;
    tile[r][tx * 4 + 2] = v.z; tile[r][tx * 4 + 3] = v.w;
  }
  __syncthreads();
  int ch = threadIdx.x & 7, cc = threadIdx.x >> 3;
#pragma unroll
  for (int pp = 0; pp < 2; pp++) {
    int c = cc + pp * 32;
    half8 h;
#pragma unroll
    for (int i = 0; i < 8; i++) h[i] = (f16)tile[ch * 8 + i][c];
    *(half8*)(op + (size_t)(c0 + c) * R + r0 + ch * 8) = h;
  }
}

// ============ GEMM1: H = gelu(Xg @ W_in + b_in), 256x256xBK64 ==============
// 2-barrier counted-vmcnt pipeline; T2 swizzled LDS; compiler-scheduled body.
__global__ __launch_bounds__(512, 1) void gemm1_k(
    const f16* __restrict__ Xh, const f16* __restrict__ Wt,
    const float* __restrict__ b_in, f16* __restrict__ H,
    const int* __restrict__ meta) {
  int G = gridDim.x;
  int wg = ((blockIdx.x & 7) * (G >> 3)) + (blockIdx.x >> 3);
  int tm = wg >> 4;            // tm-slow: 16 consecutive wg share A panel in L2
  int n0 = (wg & 15) * 256;
  int e = (meta + 256)[tm];
  if (e < 0) return;
  int row0 = (meta + 512)[tm];
  int nrows = (meta + 768)[tm];
  const int* row_tok = meta + 1024 + 2 * NSLOT;

  __shared__ __align__(16) char smem[135168];  // 128K staging | epilogue union

  int tid = threadIdx.x, lane = tid & 63, wid = tid >> 6;
  int wrow = wid >> 2, wcol = wid & 3;
  int l15 = lane & 15, l4 = lane >> 4;

  u32 aoff[4], boff[4];
#pragma unroll
  for (int p = 0; p < 4; p++) {
    int L = tid + p * 512;
    int row = L >> 3, ch = L & 7;
    int cs = ch ^ (row & 7);                       // pre-swizzled source chunk
    int rg = min(row0 + row, NSLOT - 1);
    aoff[p] = (u32)((row_tok[rg] * DMODEL + cs * 8) * 2);
    boff[p] = (u32)(((u32)(e * FFN + n0 + row) * DMODEL + cs * 8) * 2);
  }
  const char* gA = (const char*)Xh;
  const char* gB = (const char*)Wt;

  f32x4 acc[8][4];
#pragma unroll
  for (int m = 0; m < 8; m++)
#pragma unroll
    for (int n = 0; n < 4; n++) acc[m][n] = (f32x4)0.f;

  // prologue: stage kt0 -> buf0, kt1 -> buf1 (16 loads in flight)
#pragma unroll
  for (int p = 0; p < 4; p++) {
    gll16(gA + aoff[p], smem + (tid + p * 512) * 16);
    gll16(gB + boff[p], smem + 65536 + (tid + p * 512) * 16);
    aoff[p] += 128; boff[p] += 128;
  }
#pragma unroll
  for (int p = 0; p < 4; p++) {
    gll16(gA + aoff[p], smem + 32768 + (tid + p * 512) * 16);
    gll16(gB + boff[p], smem + 98304 + (tid + p * 512) * 16);
    aoff[p] += 128; boff[p] += 128;
  }

  const int NT = DMODEL / 64;  // 16

  auto iter = [&](int kt, bool issue, bool last) {
    int d = kt & 1;
    const char* cA = smem + d * 32768;
    const char* cB = smem + 65536 + d * 32768;
    if (last) asm volatile("s_waitcnt vmcnt(0)" ::: "memory");
    else      asm volatile("s_waitcnt vmcnt(8)" ::: "memory");
    __builtin_amdgcn_s_barrier();        // buf d ready for all waves
    asm volatile("" ::: "memory");       // no LDS reads hoist above barrier
    half8 a0[4][2], a1[4][2], b0[2][2], b1[2][2];
#pragma unroll
    for (int j = 0; j < 2; j++)
#pragma unroll
      for (int s = 0; s < 2; s++) {
        int r = wcol * 64 + j * 16 + l15, c = s * 4 + l4;
        b0[j][s] = *(const half8*)(cB + r * 128 + ((c ^ (r & 7)) << 4));
      }
#pragma unroll
    for (int j = 0; j < 2; j++)
#pragma unroll
      for (int s = 0; s < 2; s++) {
        int r = wcol * 64 + (2 + j) * 16 + l15, c = s * 4 + l4;
        b1[j][s] = *(const half8*)(cB + r * 128 + ((c ^ (r & 7)) << 4));
      }
#pragma unroll
    for (int i = 0; i < 4; i++)
#pragma unroll
      for (int s = 0; s < 2; s++) {
        int r = wrow * 128 + i * 16 + l15, c = s * 4 + l4;
        a0[i][s] = *(const half8*)(cA + r * 128 + ((c ^ (r & 7)) << 4));
      }
#pragma unroll
    for (int i = 0; i < 4; i++)
#pragma unroll
      for (int j = 0; j < 2; j++)
#pragma unroll
        for (int s = 0; s < 2; s++)
          acc[i][j] = __builtin_amdgcn_mfma_f32_16x16x32_f16(a0[i][s], b0[j][s], acc[i][j], 0, 0, 0);
#pragma unroll
    for (int i = 0; i < 4; i++)
#pragma unroll
      for (int j = 0; j < 2; j++)
#pragma unroll
        for (int s = 0; s < 2; s++)
          acc[i][2 + j] = __builtin_amdgcn_mfma_f32_16x16x32_f16(a0[i][s], b1[j][s], acc[i][2 + j], 0, 0, 0);
#pragma unroll
    for (int i = 0; i < 4; i++)
#pragma unroll
      for (int s = 0; s < 2; s++) {
        int r = wrow * 128 + (4 + i) * 16 + l15, c = s * 4 + l4;
        a1[i][s] = *(const half8*)(cA + r * 128 + ((c ^ (r & 7)) << 4));
      }
    asm volatile("s_waitcnt lgkmcnt(0)" ::: "memory");  // my buf-d reads retired
    __builtin_amdgcn_s_barrier();        // all waves done reading buf d
    if (issue) {
#pragma unroll
      for (int p = 0; p < 4; p++) {
        gll16(gA + aoff[p], smem + d * 32768 + (tid + p * 512) * 16);
        gll16(gB + boff[p], smem + 65536 + d * 32768 + (tid + p * 512) * 16);
        aoff[p] += 128; boff[p] += 128;
      }
    }
#pragma unroll
    for (int i = 0; i < 4; i++)
#pragma unroll
      for (int j = 0; j < 2; j++)
#pragma unroll
        for (int s = 0; s < 2; s++)
          acc[4 + i][j] = __builtin_amdgcn_mfma_f32_16x16x32_f16(a1[i][s], b0[j][s], acc[4 + i][j], 0, 0, 0);
#pragma unroll
    for (int i = 0; i < 4; i++)
#pragma unroll
      for (int j = 0; j < 2; j++)
#pragma unroll
        for (int s = 0; s < 2; s++)
          acc[4 + i][2 + j] = __builtin_amdgcn_mfma_f32_16x16x32_f16(a1[i][s], b1[j][s], acc[4 + i][2 + j], 0, 0, 0);
  };

  for (int kt = 0; kt < NT - 2; ++kt) iter(kt, true, false);
  iter(NT - 2, false, false);
  iter(NT - 1, false, true);

  // epilogue: bias+gelu -> f16 LDS repack [256][264] -> float4 stores
  float bias[4];
#pragma unroll
  for (int n = 0; n < 4; n++) bias[n] = b_in[e * FFN + n0 + wcol * 64 + n * 16 + l15];
#pragma unroll
  for (int m = 0; m < 8; m++)
#pragma unroll
    for (int n = 0; n < 4; n++)
#pragma unroll
      for (int j = 0; j < 4; j++) {
        int row = wrow * 128 + m * 16 + l4 * 4 + j;
        int col = wcol * 64 + n * 16 + l15;
        *(f16*)(smem + row * 528 + col * 2) = (f16)gelu_exact(acc[m][n][j] + bias[n]);
      }
  __syncthreads();
#pragma unroll
  for (int p = 0; p < 16; ++p) {
    int idx = tid + p * 512;
    int row = idx >> 5, cc = idx & 31;
    if (row < nrows)
      *(float4*)(H + (size_t)(row0 + row) * FFN + n0 + cc * 8) =
          *(const float4*)(smem + row * 528 + cc * 16);
  }
}

// ============ GEMM2: out[tok] += w * (H @ W_out + b_out) ==================
// 256x256, K split in 2 halves (2048 each) for grid balance; same pipeline.
__global__ __launch_bounds__(512, 1) void gemm2_k(
    const f16* __restrict__ H, const f16* __restrict__ Wt,
    const float* __restrict__ b_out, float* __restrict__ out,
    const int* __restrict__ meta) {
  int G = gridDim.x;
  int wg = ((blockIdx.x & 7) * (G >> 3)) + (blockIdx.x >> 3);
  int tm = wg >> 3;
  int r3 = wg & 7;
  int n0 = (r3 & 3) * 256;
  int ks = r3 >> 2;            // K half
  int e = (meta + 256)[tm];
  if (e < 0) return;
  int row0 = (meta + 512)[tm];
  int nrows = (meta + 768)[tm];
  const int* row_tok = meta + 1024 + 2 * NSLOT;
  const float* row_w = (const float*)(meta + 1024 + 3 * NSLOT);

  __shared__ __align__(16) char smem[131072];

  int tid = threadIdx.x, lane = tid & 63, wid = tid >> 6;
  int wrow = wid >> 2, wcol = wid & 3;
  int l15 = lane & 15, l4 = lane >> 4;
  int k0 = ks * (FFN / 2);

  u32 aoff[4], boff[4];
#pragma unroll
  for (int p = 0; p < 4; p++) {
    int L = tid + p * 512;
    int row = L >> 3, ch = L & 7;
    int cs = ch ^ (row & 7);
    u32 rg = (u32)min(row0 + row, NSLOT - 1);
    aoff[p] = (u32)((rg * FFN + k0 + cs * 8) * 2);
    boff[p] = (u32)(((u32)(e * DMODEL + n0 + row) * FFN + k0 + cs * 8) * 2);
  }
  const char* gA = (const char*)H;
  const char* gB = (const char*)Wt;

  f32x4 acc[8][4];
#pragma unroll
  for (int m = 0; m < 8; m++)
#pragma unroll
    for (int n = 0; n < 4; n++) acc[m][n] = (f32x4)0.f;

#pragma unroll
  for (int p = 0; p < 4; p++) {
    gll16(gA + aoff[p], smem + (tid + p * 512) * 16);
    gll16(gB + boff[p], smem + 65536 + (tid + p * 512) * 16);
    aoff[p] += 128; boff[p] += 128;
  }
#pragma unroll
  for (int p = 0; p < 4; p++) {
    gll16(gA + aoff[p], smem + 32768 + (tid + p * 512) * 16);
    gll16(gB + boff[p], smem + 98304 + (tid + p * 512) * 16);
    aoff[p] += 128; boff[p] += 128;
  }

  const int NT = (FFN / 2) / 64;  // 32

  auto iter = [&](int kt, bool issue, bool last) {
    int d = kt & 1;
    const char* cA = smem + d * 32768;
    const char* cB = smem + 65536 + d * 32768;
    if (last) asm volatile("s_waitcnt vmcnt(0)" ::: "memory");
    else      asm volatile("s_waitcnt vmcnt(8)" ::: "memory");
    __builtin_amdgcn_s_barrier();
    asm volatile("" ::: "memory");
    half8 a0[4][2], a1[4][2], b0[2][2], b1[2][2];
#pragma unroll
    for (int j = 0; j < 2; j++)
#pragma unroll
      for (int s = 0; s < 2; s++) {
        int r = wcol * 64 + j * 16 + l15, c = s * 4 + l4;
        b0[j][s] = *(const half8*)(cB + r * 128 + ((c ^ (r & 7)) << 4));
      }
#pragma unroll
    for (int j = 0; j < 2; j++)
#pragma unroll
      for (int s = 0; s < 2; s++) {
        int r = wcol * 64 + (2 + j) * 16 + l15, c = s * 4 + l4;
        b1[j][s] = *(const half8*)(cB + r * 128 + ((c ^ (r & 7)) << 4));
      }
#pragma unroll
    for (int i = 0; i < 4; i++)
#pragma unroll
      for (int s = 0; s < 2; s++) {
        int r = wrow * 128 + i * 16 + l15, c = s * 4 + l4;
        a0[i][s] = *(const half8*)(cA + r * 128 + ((c ^ (r & 7)) << 4));
      }
#pragma unroll
    for (int i = 0; i < 4; i++)
#pragma unroll
      for (int j = 0; j < 2; j++)
#pragma unroll
        for (int s = 0; s < 2; s++)
          acc[i][j] = __builtin_amdgcn_mfma_f32_16x16x32_f16(a0[i][s], b0[j][s], acc[i][j], 0, 0, 0);
#pragma unroll
    for (int i = 0; i < 4; i++)
#pragma unroll
      for (int j = 0; j < 2; j++)
#pragma unroll
        for (int s = 0; s < 2; s++)
          acc[i][2 + j] = __builtin_amdgcn_mfma_f32_16x16x32_f16(a0[i][s], b1[j][s], acc[i][2 + j], 0, 0, 0);
#pragma unroll
    for (int i = 0; i < 4; i++)
#pragma unroll
      for (int s = 0; s < 2; s++) {
        int r = wrow * 128 + (4 + i) * 16 + l15, c = s * 4 + l4;
        a1[i][s] = *(const half8*)(cA + r * 128 + ((c ^ (r & 7)) << 4));
      }
    asm volatile("s_waitcnt lgkmcnt(0)" ::: "memory");
    __builtin_amdgcn_s_barrier();
    if (issue) {
#pragma unroll
      for (int p = 0; p < 4; p++) {
        gll16(gA + aoff[p], smem + d * 32768 + (tid + p * 512) * 16);
        gll16(gB + boff[p], smem + 65536 + d * 32768 + (tid + p * 512) * 16);
        aoff[p] += 128; boff[p] += 128;
      }
    }
#pragma unroll
    for (int i = 0; i < 4; i++)
#pragma unroll
      for (int j = 0; j < 2; j++)
#pragma unroll
        for (int s = 0; s < 2; s++)
          acc[4 + i][j] = __builtin_amdgcn_mfma_f32_16x16x32_f16(a1[i][s], b0[j][s], acc[4 + i][j], 0, 0, 0);
#pragma unroll
    for (int i = 0; i < 4; i++)
#pragma unroll
      for (int j = 0; j < 2; j++)
#pragma unroll
        for (int s = 0; s < 2; s++)
          acc[4 + i][2 + j] = __builtin_amdgcn_mfma_f32_16x16x32_f16(a1[i][s], b1[j][s], acc[4 + i][2 + j], 0, 0, 0);
  };

  for (int kt = 0; kt < NT - 2; ++kt) iter(kt, true, false);
  iter(NT - 2, false, false);
  iter(NT - 1, false, true);

  float bias[4];
#pragma unroll
  for (int n = 0; n < 4; n++)
    bias[n] = (ks == 0) ? b_out[e * DMODEL + n0 + wcol * 64 + n * 16 + l15] : 0.f;
#pragma unroll
  for (int m = 0; m < 8; m++)
#pragma unroll
    for (int j = 0; j < 4; j++) {
      int r = wrow * 128 + m * 16 + l4 * 4 + j;
      if (r < nrows) {
        int rg = row0 + r;
        int tok = row_tok[rg];
        float w = row_w[rg];
#pragma unroll
        for (int n = 0; n < 4; n++)
          atomicAdd(out + (size_t)tok * DMODEL + n0 + wcol * 64 + n * 16 + l15,
                    w * (acc[m][n][j] + bias[n]));
      }
    }
}

// ---------------- fallback (small workspace) -------------------------------
__global__ __launch_bounds__(256) void naive_k(
    const float* __restrict__ x, const float* __restrict__ W_in,
    const float* __restrict__ b_in, const float* __restrict__ W_out,
    const float* __restrict__ b_out, const int* __restrict__ sel_e,
    const float* __restrict__ sel_w, float* __restrict__ out) {
  int s = blockIdx.x;
  int t = s >> 1;
  int e = sel_e[s];
  float w = sel_w[s];
  __shared__ float xs[DMODEL];
  __shared__ float hs[FFN];
  int tid = threadIdx.x;
  for (int d = tid; d < DMODEL; d += 256) xs[d] = x[(size_t)t * DMODEL + d];
  __syncthreads();
  for (int f = tid; f < FFN; f += 256) {
    float a = b_in[e * FFN + f];
    const float* wp = W_in + (size_t)e * DMODEL * FFN + f;
    for (int d = 0; d < DMODEL; d++) a += xs[d] * wp[(size_t)d * FFN];
    hs[f] = gelu_exact(a);
  }
  __syncthreads();
  for (int d = tid; d < DMODEL; d += 256) {
    float a = b_out[e * DMODEL + d];
    const float* wp = W_out + (size_t)e * FFN * DMODEL + d;
    for (int f = 0; f < FFN; f++) a += hs[f] * wp[(size_t)f * DMODEL];
    atomicAdd(&out[(size_t)t * DMODEL + d], w * a);
  }
}

extern "C" void kernel_launch(void* const* d_in, const int* in_sizes, int n_in,
                              void* d_out, int out_size, void* d_ws, size_t ws_size,
                              hipStream_t stream) {
  const float* residual = (const float*)d_in[0];
  const float* W_router = (const float*)d_in[1];
  const float* W_in = (const float*)d_in[2];
  const float* b_in = (const float*)d_in[3];
  const float* W_out = (const float*)d_in[4];
  const float* b_out = (const float*)d_in[5];
  float* out = (float*)d_out;

  char* ws = (char*)d_ws;
  int* meta = (int*)ws;
  size_t off = (size_t)1 << 20;
  f16* Xh = (f16*)(ws + off); off += (size_t)T_TOK * DMODEL * 2;       // 16 MB
  f16* Wih = (f16*)(ws + off); off += (size_t)NEXP * DMODEL * FFN * 2; // 64 MB
  f16* Woh = (f16*)(ws + off); off += (size_t)NEXP * DMODEL * FFN * 2; // 64 MB
  f16* H = (f16*)(ws + off); off += (size_t)NSLOT * FFN * 2;           // 128 MB
  off += 65536;                                                        // OOB-read slack
  bool fast = ws_size >= off;

  int* sel_e = meta + 1024;
  float* sel_w = (float*)(meta + 1024 + NSLOT);
  int* row_tok = meta + 1024 + 2 * NSLOT;
  float* row_w = (float*)(meta + 1024 + 3 * NSLOT);

  hipMemsetAsync(meta, 0, 4096, stream);
  hipMemsetAsync(d_out, 0, (size_t)out_size * sizeof(float), stream);

  router_k<<<T_TOK / 4, 256, 0, stream>>>(residual, W_router, sel_e, sel_w, meta);

  if (fast) {
    cvtx_k<<<(T_TOK * DMODEL / 8) / 256, 256, 0, stream>>>(residual, Xh);
    transq_k<<<dim3(FFN / 64, DMODEL / 64, NEXP), 256, 0, stream>>>(W_in, Wih, DMODEL, FFN);
    transq_k<<<dim3(DMODEL / 64, FFN / 64, NEXP), 256, 0, stream>>>(W_out, Woh, FFN, DMODEL);
    sched_k<<<1, 1, 0, stream>>>(meta);
    scatter_k<<<NSLOT / 256, 256, 0, stream>>>(sel_e, sel_w, meta + 128, meta + 64,
                                               row_tok, row_w);
    gemm1_k<<<MAXT * 16, 512, 0, stream>>>(Xh, Wih, b_in, H, meta);
    gemm2_k<<<MAXT * 8, 512, 0, stream>>>(H, Woh, b_out, out, meta);
  } else {
    naive_k<<<NSLOT, 256, 0, stream>>>(residual, W_in, b_in, W_out, b_out,
                                       sel_e, sel_w, out);
  }
}

// Round 5
// 830.168 us; speedup vs baseline: 1.1062x; 1.0888x over previous
//
#include <hip/hip_runtime.h>
#include <hip/hip_bf16.h>
#include <math.h>

#define T_TOK 8192
#define DMODEL 1024
#define FFN 4096
#define NEXP 8
#define NSLOT (T_TOK * 2)
#define MAXT 72  // sum ceil(c_e/256) <= 64+8 = 72

typedef _Float16 f16;
typedef _Float16 half8 __attribute__((ext_vector_type(8)));
typedef float f32x4 __attribute__((ext_vector_type(4)));
typedef unsigned int u32;

__device__ __forceinline__ void gll16(const void* g, void* l) {
  __builtin_amdgcn_global_load_lds(
      (const __attribute__((address_space(1))) u32*)g,
      (__attribute__((address_space(3))) u32*)l, 16, 0, 0);
}

__device__ __forceinline__ float gelu_exact(float v) {
  return 0.5f * v * (1.0f + erff(v * 0.70710678118654752f));
}

// swizzle: 4 chunks of 16B per 64B row; distributes 16 rows over banks 2-way
__device__ __forceinline__ int swz4(int ch, int row) {
  return ch ^ (row & 3) ^ ((row >> 2) & 3);
}

// ---------------- router ---------------------------------------------------
__global__ __launch_bounds__(256) void router_k(
    const float* __restrict__ x, const float* __restrict__ Wr,
    int* __restrict__ sel_e, float* __restrict__ sel_w, int* __restrict__ counts) {
  int t = blockIdx.x * 4 + (threadIdx.x >> 6);
  int lane = threadIdx.x & 63;
  const float* xp = x + (size_t)t * DMODEL;
  float p[NEXP];
#pragma unroll
  for (int e = 0; e < NEXP; e++) p[e] = 0.f;
#pragma unroll
  for (int i = 0; i < DMODEL / 64; i++) {
    float xv = xp[lane + i * 64];
#pragma unroll
    for (int e = 0; e < NEXP; e++) p[e] += xv * Wr[e * DMODEL + lane + i * 64];
  }
#pragma unroll
  for (int off = 32; off; off >>= 1) {
#pragma unroll
    for (int e = 0; e < NEXP; e++) p[e] += __shfl_xor(p[e], off);
  }
  if (lane == 0) {
    float l0 = -1e30f, l1 = -1e30f;
    int e0 = 0, e1 = 1;
#pragma unroll
    for (int e = 0; e < NEXP; e++) {
      if (p[e] > l0) { l1 = l0; e1 = e0; l0 = p[e]; e0 = e; }
      else if (p[e] > l1) { l1 = p[e]; e1 = e; }
    }
    float r = expf(l1 - l0);
    float inv = 1.f / (1.f + r);
    sel_e[t * 2] = e0;     sel_w[t * 2] = inv;
    sel_e[t * 2 + 1] = e1; sel_w[t * 2 + 1] = r * inv;
    atomicAdd(&counts[e0], 1);
    atomicAdd(&counts[e1], 1);
  }
}

// ---------------- schedule (256-row tiles) ---------------------------------
__global__ void sched_k(int* meta) {
  int* counts = meta;
  int* fill = meta + 64;
  int* offs = meta + 128;
  int* tE = meta + 256;
  int* tR0 = meta + 512;
  int* tRows = meta + 768;
  int off = 0, nt = 0;
  for (int e = 0; e < NEXP; e++) {
    offs[e] = off;
    fill[e] = 0;
    int c = counts[e];
    for (int t0 = 0; t0 < c; t0 += 256) {
      tE[nt] = e; tR0[nt] = off + t0; tRows[nt] = min(256, c - t0); nt++;
    }
    off += c;
  }
  offs[NEXP] = off;
  for (; nt < MAXT; nt++) tE[nt] = -1;
}

// ---------------- scatter --------------------------------------------------
__global__ __launch_bounds__(256) void scatter_k(
    const int* __restrict__ sel_e, const float* __restrict__ sel_w,
    const int* __restrict__ offs, int* fill,
    int* __restrict__ row_tok, float* __restrict__ row_w) {
  int s = blockIdx.x * 256 + threadIdx.x;
  int e = sel_e[s];
  int pos = atomicAdd(&fill[e], 1);
  int r = offs[e] + pos;
  row_tok[r] = s >> 1;
  row_w[r] = sel_w[s];
}

// ---------------- f32 -> f16 elementwise (x) -------------------------------
__global__ __launch_bounds__(256) void cvtx_k(const float* __restrict__ x,
                                              f16* __restrict__ xh) {
  int i = blockIdx.x * 256 + threadIdx.x;
  const float4* src = (const float4*)x;
  float4 a = src[i * 2], b = src[i * 2 + 1];
  half8 h;
  h[0] = (f16)a.x; h[1] = (f16)a.y; h[2] = (f16)a.z; h[3] = (f16)a.w;
  h[4] = (f16)b.x; h[5] = (f16)b.y; h[6] = (f16)b.z; h[7] = (f16)b.w;
  ((half8*)xh)[i] = h;
}

// ------------- transpose+convert 64x64: out[e][c][r] = (f16) in[e][r][c] ---
__global__ __launch_bounds__(256) void transq_k(const float* __restrict__ in,
                                                f16* __restrict__ out, int R, int C) {
  __shared__ float tile[64][69];
  int e = blockIdx.z;
  const float* ip = in + (size_t)e * R * C;
  f16* op = out + (size_t)e * R * C;
  int c0 = blockIdx.x * 64, r0 = blockIdx.y * 64;
  int tx = threadIdx.x & 15, ty = threadIdx.x >> 4;
#pragma unroll
  for (int rr = 0; rr < 4; rr++) {
    float4 v = *(const float4*)(ip + (size_t)(r0 + ty + rr * 16) * C + c0 + tx * 4);
    int r = ty + rr * 16;
    tile[r][tx * 4 + 0] = v.x; tile[r][tx * 4 + 1] = v.y;
    tile[r][tx * 4 + 2] = v.z; tile[r][tx * 4 + 3] = v.w;
  }
  __syncthreads();
  int ch = threadIdx.x & 7, cc = threadIdx.x >> 3;
#pragma unroll
  for (int pp = 0; pp < 2; pp++) {
    int c = cc + pp * 32;
    half8 h;
#pragma unroll
    for (int i = 0; i < 8; i++) h[i] = (f16)tile[ch * 8 + i][c];
    *(half8*)(op + (size_t)(c0 + c) * R + r0 + ch * 8) = h;
  }
}

// ============ GEMM1: H = gelu(Xg @ W_in + b_in) ===========================
// tile 256x128, BK=32, 8 waves (4x2), wave-tile 64x64, dbuf 48KB, 2 blk/CU.
__global__ __launch_bounds__(512, 4) void gemm1_k(
    const f16* __restrict__ Xh, const f16* __restrict__ Wt,
    const float* __restrict__ b_in, f16* __restrict__ H,
    const int* __restrict__ meta) {
  int G = gridDim.x;
  int wg = ((blockIdx.x & 7) * (G >> 3)) + (blockIdx.x >> 3);
  int tm = wg >> 5;            // 32 consecutive wg share the 0.5 MB A panel
  int n0 = (wg & 31) * 128;
  int e = (meta + 256)[tm];
  if (e < 0) return;
  int row0 = (meta + 512)[tm];
  int nrows = (meta + 768)[tm];
  const int* row_tok = meta + 1024 + 2 * NSLOT;

  __shared__ __align__(16) char smem[49152];  // A dbuf 32K | B dbuf 16K

  int tid = threadIdx.x, lane = tid & 63, wid = tid >> 6;
  int wrow = wid >> 1, wcol = wid & 1;
  int l15 = lane & 15, l4 = lane >> 4;

  // staging offsets (pre-swizzled global source, linear LDS dest)
  u32 aoff0, aoff1, boff;
  {
    int r0a = tid >> 2, c0a = swz4(tid & 3, r0a);
    int r1a = (tid + 512) >> 2, c1a = swz4(tid & 3, r1a);
    aoff0 = (u32)((row_tok[min(row0 + r0a, NSLOT - 1)] * DMODEL + c0a * 8) * 2);
    aoff1 = (u32)((row_tok[min(row0 + r1a, NSLOT - 1)] * DMODEL + c1a * 8) * 2);
    int rb = tid >> 2, cb = swz4(tid & 3, rb);
    boff = (u32)(((u32)(e * FFN + n0 + rb) * DMODEL + cb * 8) * 2);
  }
  const char* gA = (const char*)Xh;
  const char* gB = (const char*)Wt;

  // precomputed swizzled fragment read offsets
  int aaddr[4], baddr[4];
#pragma unroll
  for (int i = 0; i < 4; i++) {
    int r = wrow * 64 + i * 16 + l15;
    aaddr[i] = r * 64 + (swz4(l4, r) << 4);
  }
#pragma unroll
  for (int j = 0; j < 4; j++) {
    int r = wcol * 64 + j * 16 + l15;
    baddr[j] = r * 64 + (swz4(l4, r) << 4);
  }

  f32x4 acc[4][4];
#pragma unroll
  for (int m = 0; m < 4; m++)
#pragma unroll
    for (int n = 0; n < 4; n++) acc[m][n] = (f32x4)0.f;

  auto stage = [&](int d) {
    gll16(gA + aoff0, smem + d * 16384 + tid * 16);
    gll16(gA + aoff1, smem + d * 16384 + 8192 + tid * 16);
    gll16(gB + boff, smem + 32768 + d * 8192 + tid * 16);
    aoff0 += 64; aoff1 += 64; boff += 64;
  };

  stage(0);
  stage(1);

  const int NT = DMODEL / 32;  // 32
  for (int kt = 0; kt < NT; ++kt) {
    int d = kt & 1;
    const char* cA = smem + d * 16384;
    const char* cB = smem + 32768 + d * 8192;
    if (kt == NT - 1) asm volatile("s_waitcnt vmcnt(0)" ::: "memory");
    else              asm volatile("s_waitcnt vmcnt(3)" ::: "memory");
    __builtin_amdgcn_s_barrier();
    asm volatile("" ::: "memory");
    half8 a[4], b[4];
#pragma unroll
    for (int i = 0; i < 4; i++) a[i] = *(const half8*)(cA + aaddr[i]);
#pragma unroll
    for (int j = 0; j < 4; j++) b[j] = *(const half8*)(cB + baddr[j]);
#pragma unroll
    for (int i = 0; i < 4; i++)
#pragma unroll
      for (int j = 0; j < 4; j++)
        acc[i][j] = __builtin_amdgcn_mfma_f32_16x16x32_f16(a[i], b[j], acc[i][j], 0, 0, 0);
    asm volatile("s_waitcnt lgkmcnt(0)" ::: "memory");
    __builtin_amdgcn_s_barrier();
    if (kt < NT - 2) stage(d);
  }

  // epilogue: bias+gelu -> LDS repack (2 chunks of 128 rows) -> float4 stores
  float bias[4];
#pragma unroll
  for (int n = 0; n < 4; n++) bias[n] = b_in[e * FFN + n0 + wcol * 64 + n * 16 + l15];
#pragma unroll
  for (int c = 0; c < 2; ++c) {
    if ((wrow >> 1) == c) {
#pragma unroll
      for (int m = 0; m < 4; m++)
#pragma unroll
        for (int n = 0; n < 4; n++)
#pragma unroll
          for (int j = 0; j < 4; j++) {
            int lrow = (wrow & 1) * 64 + m * 16 + l4 * 4 + j;
            *(f16*)(smem + lrow * 272 + (wcol * 64 + n * 16 + l15) * 2) =
                (f16)gelu_exact(acc[m][n][j] + bias[n]);
          }
    }
    __syncthreads();
#pragma unroll
    for (int p = 0; p < 4; ++p) {
      int idx = tid + p * 512;
      int r = idx >> 4, cc = idx & 15;
      if (c * 128 + r < nrows)
        *(float4*)(H + (size_t)(row0 + c * 128 + r) * FFN + n0 + cc * 8) =
            *(const float4*)(smem + r * 272 + cc * 16);
    }
    __syncthreads();
  }
}

// ============ GEMM2: out[tok] += w * (H @ W_out + b_out) ==================
// tile 256x128, BK=32, 8 waves, wave-tile 64x64; 512 working blocks = 2/CU.
__global__ __launch_bounds__(512, 4) void gemm2_k(
    const f16* __restrict__ H, const f16* __restrict__ Wt,
    const float* __restrict__ b_out, float* __restrict__ out,
    const int* __restrict__ meta) {
  int G = gridDim.x;
  int wg = ((blockIdx.x & 7) * (G >> 3)) + (blockIdx.x >> 3);
  int tm = wg >> 3;            // 8 consecutive wg share the 2 MB A panel
  int n0 = (wg & 7) * 128;
  int e = (meta + 256)[tm];
  if (e < 0) return;
  int row0 = (meta + 512)[tm];
  int nrows = (meta + 768)[tm];
  const int* row_tok = meta + 1024 + 2 * NSLOT;
  const float* row_w = (const float*)(meta + 1024 + 3 * NSLOT);

  __shared__ __align__(16) char smem[49152];

  int tid = threadIdx.x, lane = tid & 63, wid = tid >> 6;
  int wrow = wid >> 1, wcol = wid & 1;
  int l15 = lane & 15, l4 = lane >> 4;

  u32 aoff0, aoff1, boff;
  {
    int r0a = tid >> 2, c0a = swz4(tid & 3, r0a);
    int r1a = (tid + 512) >> 2, c1a = swz4(tid & 3, r1a);
    aoff0 = (u32)(((u32)min(row0 + r0a, NSLOT - 1) * FFN + c0a * 8) * 2);
    aoff1 = (u32)(((u32)min(row0 + r1a, NSLOT - 1) * FFN + c1a * 8) * 2);
    int rb = tid >> 2, cb = swz4(tid & 3, rb);
    boff = (u32)(((u32)(e * DMODEL + n0 + rb) * FFN + cb * 8) * 2);
  }
  const char* gA = (const char*)H;
  const char* gB = (const char*)Wt;

  int aaddr[4], baddr[4];
#pragma unroll
  for (int i = 0; i < 4; i++) {
    int r = wrow * 64 + i * 16 + l15;
    aaddr[i] = r * 64 + (swz4(l4, r) << 4);
  }
#pragma unroll
  for (int j = 0; j < 4; j++) {
    int r = wcol * 64 + j * 16 + l15;
    baddr[j] = r * 64 + (swz4(l4, r) << 4);
  }

  f32x4 acc[4][4];
#pragma unroll
  for (int m = 0; m < 4; m++)
#pragma unroll
    for (int n = 0; n < 4; n++) acc[m][n] = (f32x4)0.f;

  auto stage = [&](int d) {
    gll16(gA + aoff0, smem + d * 16384 + tid * 16);
    gll16(gA + aoff1, smem + d * 16384 + 8192 + tid * 16);
    gll16(gB + boff, smem + 32768 + d * 8192 + tid * 16);
    aoff0 += 64; aoff1 += 64; boff += 64;
  };

  stage(0);
  stage(1);

  const int NT = FFN / 32;  // 128
  for (int kt = 0; kt < NT; ++kt) {
    int d = kt & 1;
    const char* cA = smem + d * 16384;
    const char* cB = smem + 32768 + d * 8192;
    if (kt == NT - 1) asm volatile("s_waitcnt vmcnt(0)" ::: "memory");
    else              asm volatile("s_waitcnt vmcnt(3)" ::: "memory");
    __builtin_amdgcn_s_barrier();
    asm volatile("" ::: "memory");
    half8 a[4], b[4];
#pragma unroll
    for (int i = 0; i < 4; i++) a[i] = *(const half8*)(cA + aaddr[i]);
#pragma unroll
    for (int j = 0; j < 4; j++) b[j] = *(const half8*)(cB + baddr[j]);
#pragma unroll
    for (int i = 0; i < 4; i++)
#pragma unroll
      for (int j = 0; j < 4; j++)
        acc[i][j] = __builtin_amdgcn_mfma_f32_16x16x32_f16(a[i], b[j], acc[i][j], 0, 0, 0);
    asm volatile("s_waitcnt lgkmcnt(0)" ::: "memory");
    __builtin_amdgcn_s_barrier();
    if (kt < NT - 2) stage(d);
  }

  float bias[4];
#pragma unroll
  for (int n = 0; n < 4; n++) bias[n] = b_out[e * DMODEL + n0 + wcol * 64 + n * 16 + l15];
#pragma unroll
  for (int m = 0; m < 4; m++)
#pragma unroll
    for (int j = 0; j < 4; j++) {
      int r = wrow * 64 + m * 16 + l4 * 4 + j;
      if (r < nrows) {
        int rg = row0 + r;
        int tok = row_tok[rg];
        float w = row_w[rg];
#pragma unroll
        for (int n = 0; n < 4; n++)
          atomicAdd(out + (size_t)tok * DMODEL + n0 + wcol * 64 + n * 16 + l15,
                    w * (acc[m][n][j] + bias[n]));
      }
    }
}

// ---------------- fallback (small workspace) -------------------------------
__global__ __launch_bounds__(256) void naive_k(
    const float* __restrict__ x, const float* __restrict__ W_in,
    const float* __restrict__ b_in, const float* __restrict__ W_out,
    const float* __restrict__ b_out, const int* __restrict__ sel_e,
    const float* __restrict__ sel_w, float* __restrict__ out) {
  int s = blockIdx.x;
  int t = s >> 1;
  int e = sel_e[s];
  float w = sel_w[s];
  __shared__ float xs[DMODEL];
  __shared__ float hs[FFN];
  int tid = threadIdx.x;
  for (int d = tid; d < DMODEL; d += 256) xs[d] = x[(size_t)t * DMODEL + d];
  __syncthreads();
  for (int f = tid; f < FFN; f += 256) {
    float a = b_in[e * FFN + f];
    const float* wp = W_in + (size_t)e * DMODEL * FFN + f;
    for (int d = 0; d < DMODEL; d++) a += xs[d] * wp[(size_t)d * FFN];
    hs[f] = gelu_exact(a);
  }
  __syncthreads();
  for (int d = tid; d < DMODEL; d += 256) {
    float a = b_out[e * DMODEL + d];
    const float* wp = W_out + (size_t)e * FFN * DMODEL + d;
    for (int f = 0; f < FFN; f++) a += hs[f] * wp[(size_t)f * DMODEL];
    atomicAdd(&out[(size_t)t * DMODEL + d], w * a);
  }
}

extern "C" void kernel_launch(void* const* d_in, const int* in_sizes, int n_in,
                              void* d_out, int out_size, void* d_ws, size_t ws_size,
                              hipStream_t stream) {
  const float* residual = (const float*)d_in[0];
  const float* W_router = (const float*)d_in[1];
  const float* W_in = (const float*)d_in[2];
  const float* b_in = (const float*)d_in[3];
  const float* W_out = (const float*)d_in[4];
  const float* b_out = (const float*)d_in[5];
  float* out = (float*)d_out;

  char* ws = (char*)d_ws;
  int* meta = (int*)ws;
  size_t off = (size_t)1 << 20;
  f16* Xh = (f16*)(ws + off); off += (size_t)T_TOK * DMODEL * 2;       // 16 MB
  f16* Wih = (f16*)(ws + off); off += (size_t)NEXP * DMODEL * FFN * 2; // 64 MB
  f16* Woh = (f16*)(ws + off); off += (size_t)NEXP * DMODEL * FFN * 2; // 64 MB
  f16* H = (f16*)(ws + off); off += (size_t)NSLOT * FFN * 2;           // 128 MB
  off += 65536;                                                        // OOB-read slack
  bool fast = ws_size >= off;

  int* sel_e = meta + 1024;
  float* sel_w = (float*)(meta + 1024 + NSLOT);
  int* row_tok = meta + 1024 + 2 * NSLOT;
  float* row_w = (float*)(meta + 1024 + 3 * NSLOT);

  hipMemsetAsync(meta, 0, 4096, stream);
  hipMemsetAsync(d_out, 0, (size_t)out_size * sizeof(float), stream);

  router_k<<<T_TOK / 4, 256, 0, stream>>>(residual, W_router, sel_e, sel_w, meta);

  if (fast) {
    cvtx_k<<<(T_TOK * DMODEL / 8) / 256, 256, 0, stream>>>(residual, Xh);
    transq_k<<<dim3(FFN / 64, DMODEL / 64, NEXP), 256, 0, stream>>>(W_in, Wih, DMODEL, FFN);
    transq_k<<<dim3(DMODEL / 64, FFN / 64, NEXP), 256, 0, stream>>>(W_out, Woh, FFN, DMODEL);
    sched_k<<<1, 1, 0, stream>>>(meta);
    scatter_k<<<NSLOT / 256, 256, 0, stream>>>(sel_e, sel_w, meta + 128, meta + 64,
                                               row_tok, row_w);
    gemm1_k<<<MAXT * 32, 512, 0, stream>>>(Xh, Wih, b_in, H, meta);
    gemm2_k<<<MAXT * 8, 512, 0, stream>>>(H, Woh, b_out, out, meta);
  } else {
    naive_k<<<NSLOT, 256, 0, stream>>>(residual, W_in, b_in, W_out, b_out,
                                       sel_e, sel_w, out);
  }
}

// Round 6
// 765.177 us; speedup vs baseline: 1.2002x; 1.0849x over previous
//
#include <hip/hip_runtime.h>
#include <hip/hip_bf16.h>
#include <math.h>

#define T_TOK 8192
#define DMODEL 1024
#define FFN 4096
#define NEXP 8
#define NSLOT (T_TOK * 2)
#define MAXT 136  // sum ceil(c_e/128) <= 16384/128 + 8 = 136

typedef _Float16 f16;
typedef _Float16 half8 __attribute__((ext_vector_type(8)));
typedef float f32x4 __attribute__((ext_vector_type(4)));
typedef unsigned int u32;

__device__ __forceinline__ void gll16(const void* g, void* l) {
  __builtin_amdgcn_global_load_lds(
      (const __attribute__((address_space(1))) u32*)g,
      (__attribute__((address_space(3))) u32*)l, 16, 0, 0);
}

__device__ __forceinline__ float gelu_exact(float v) {
  return 0.5f * v * (1.0f + erff(v * 0.70710678118654752f));
}

// ---------------- router (+ fused f32->f16 conversion of x) ----------------
__global__ __launch_bounds__(256) void router_k(
    const float* __restrict__ x, const float* __restrict__ Wr,
    int* __restrict__ sel_e, float* __restrict__ sel_w, int* __restrict__ counts,
    f16* __restrict__ xh) {
  int t = blockIdx.x * 4 + (threadIdx.x >> 6);
  int lane = threadIdx.x & 63;
  const float* xp = x + (size_t)t * DMODEL;
  f16* xhp = xh + (size_t)t * DMODEL;
  float p[NEXP];
#pragma unroll
  for (int e = 0; e < NEXP; e++) p[e] = 0.f;
#pragma unroll
  for (int i = 0; i < DMODEL / 64; i++) {
    float xv = xp[lane + i * 64];
    xhp[lane + i * 64] = (f16)xv;
#pragma unroll
    for (int e = 0; e < NEXP; e++) p[e] += xv * Wr[e * DMODEL + lane + i * 64];
  }
#pragma unroll
  for (int off = 32; off; off >>= 1) {
#pragma unroll
    for (int e = 0; e < NEXP; e++) p[e] += __shfl_xor(p[e], off);
  }
  if (lane == 0) {
    float l0 = -1e30f, l1 = -1e30f;
    int e0 = 0, e1 = 1;
#pragma unroll
    for (int e = 0; e < NEXP; e++) {
      if (p[e] > l0) { l1 = l0; e1 = e0; l0 = p[e]; e0 = e; }
      else if (p[e] > l1) { l1 = p[e]; e1 = e; }
    }
    float r = expf(l1 - l0);
    float inv = 1.f / (1.f + r);
    sel_e[t * 2] = e0;     sel_w[t * 2] = inv;
    sel_e[t * 2 + 1] = e1; sel_w[t * 2 + 1] = r * inv;
    atomicAdd(&counts[e0], 1);
    atomicAdd(&counts[e1], 1);
  }
}

// ---------------- schedule (128-row tiles) ---------------------------------
__global__ void sched_k(int* meta) {
  int* counts = meta;
  int* fill = meta + 64;
  int* offs = meta + 128;
  int* tE = meta + 256;
  int* tR0 = meta + 512;
  int* tRows = meta + 768;
  int off = 0, nt = 0;
  for (int e = 0; e < NEXP; e++) {
    offs[e] = off;
    fill[e] = 0;
    int c = counts[e];
    for (int t0 = 0; t0 < c; t0 += 128) {
      tE[nt] = e; tR0[nt] = off + t0; tRows[nt] = min(128, c - t0); nt++;
    }
    off += c;
  }
  offs[NEXP] = off;
  for (; nt < MAXT; nt++) tE[nt] = -1;
}

// ---------------- scatter --------------------------------------------------
__global__ __launch_bounds__(256) void scatter_k(
    const int* __restrict__ sel_e, const float* __restrict__ sel_w,
    const int* __restrict__ offs, int* fill,
    int* __restrict__ row_tok, float* __restrict__ row_w) {
  int s = blockIdx.x * 256 + threadIdx.x;
  int e = sel_e[s];
  int pos = atomicAdd(&fill[e], 1);
  int r = offs[e] + pos;
  row_tok[r] = s >> 1;
  row_w[r] = sel_w[s];
}

// ------------- transpose+convert 64x64: out[e][c][r] = (f16) in[e][r][c] ---
__global__ __launch_bounds__(256) void transq_k(const float* __restrict__ in,
                                                f16* __restrict__ out, int R, int C) {
  __shared__ float tile[64][69];
  int e = blockIdx.z;
  const float* ip = in + (size_t)e * R * C;
  f16* op = out + (size_t)e * R * C;
  int c0 = blockIdx.x * 64, r0 = blockIdx.y * 64;
  int tx = threadIdx.x & 15, ty = threadIdx.x >> 4;
#pragma unroll
  for (int rr = 0; rr < 4; rr++) {
    float4 v = *(const float4*)(ip + (size_t)(r0 + ty + rr * 16) * C + c0 + tx * 4);
    int r = ty + rr * 16;
    tile[r][tx * 4 + 0] = v.x; tile[r][tx * 4 + 1] = v.y;
    tile[r][tx * 4 + 2] = v.z; tile[r][tx * 4 + 3] = v.w;
  }
  __syncthreads();
  int ch = threadIdx.x & 7, cc = threadIdx.x >> 3;
#pragma unroll
  for (int pp = 0; pp < 2; pp++) {
    int c = cc + pp * 32;
    half8 h;
#pragma unroll
    for (int i = 0; i < 8; i++) h[i] = (f16)tile[ch * 8 + i][c];
    *(half8*)(op + (size_t)(c0 + c) * R + r0 + ch * 8) = h;
  }
}

// ============ GEMM1: H = gelu(Xg @ W_in + b_in) ===========================
// m97 structure: 128x128 tile, BK=64, 4 waves, single-buffer, 2 syncs/kt,
// proven zero-conflict XOR layout (128B rows, ch^(r&7)), ~3 blocks/CU.
__global__ __launch_bounds__(256, 3) void gemm1_k(
    const f16* __restrict__ Xh, const f16* __restrict__ Wt,
    const float* __restrict__ b_in, f16* __restrict__ H,
    const int* __restrict__ meta) {
  int xcd = blockIdx.x & 7, bidx = blockIdx.x >> 3;
  int wg = xcd * (gridDim.x >> 3) + bidx;   // chunked-bijective XCD swizzle
  int tm = wg % MAXT;                        // fast: B panel L2-hot per XCD
  int n0 = (wg / MAXT) * 128;
  int e = (meta + 256)[tm];
  if (e < 0) return;
  int row0 = (meta + 512)[tm];
  int nrows = (meta + 768)[tm];
  const int* row_tok = meta + 1024 + 2 * NSLOT;

  __shared__ __align__(16) char smem[33792];  // 16K A | 16K B ; union: 128x264B

  int tid = threadIdx.x, lane = tid & 63, wid = tid >> 6;
  int wrow = wid >> 1, wcol = wid & 1;
  int l15 = lane & 15, l4 = lane >> 4;

  u32 aoffs[4], boffs[4];
#pragma unroll
  for (int p = 0; p < 4; p++) {
    int L = tid + p * 256;
    int row = L >> 3, ch = L & 7;
    int cs = ch ^ (row & 7);
    aoffs[p] = (u32)(row_tok[min(row0 + row, NSLOT - 1)] * (DMODEL * 2) + cs * 16);
    boffs[p] = (u32)((e * FFN + n0 + row) * (DMODEL * 2) + cs * 16);
  }
  const char* gA = (const char*)Xh;
  const char* gB = (const char*)Wt;

  f32x4 acc[4][4];
#pragma unroll
  for (int m = 0; m < 4; m++)
#pragma unroll
    for (int n = 0; n < 4; n++) acc[m][n] = (f32x4)0.f;

  const int NT = DMODEL / 64;  // 16
  for (int kt = 0; kt < NT; ++kt) {
#pragma unroll
    for (int p = 0; p < 4; p++) {
      gll16(gA + aoffs[p], smem + (tid + p * 256) * 16);
      gll16(gB + boffs[p], smem + 16384 + (tid + p * 256) * 16);
      aoffs[p] += 128; boffs[p] += 128;
    }
    __syncthreads();  // drains vmcnt -> tile ready
#pragma unroll
    for (int s = 0; s < 2; s++) {
      int swz = ((s * 4 + l4) ^ (l15 & 7)) << 4;
      const char* pA = smem + (wrow * 64 + l15) * 128 + swz;
      const char* pB = smem + 16384 + (wcol * 64 + l15) * 128 + swz;
      half8 a[4], b[4];
#pragma unroll
      for (int i = 0; i < 4; i++) a[i] = *(const half8*)(pA + i * 2048);
#pragma unroll
      for (int j = 0; j < 4; j++) b[j] = *(const half8*)(pB + j * 2048);
#pragma unroll
      for (int i = 0; i < 4; i++)
#pragma unroll
        for (int j = 0; j < 4; j++)
          acc[i][j] = __builtin_amdgcn_mfma_f32_16x16x32_f16(a[i], b[j], acc[i][j], 0, 0, 0);
    }
    __syncthreads();  // all reads done before next stage overwrites
  }

  // epilogue: bias+gelu -> LDS repack [128][132 f16] -> float4 stores
  float bias[4];
#pragma unroll
  for (int n = 0; n < 4; n++) bias[n] = b_in[e * FFN + n0 + wcol * 64 + n * 16 + l15];
#pragma unroll
  for (int m = 0; m < 4; m++)
#pragma unroll
    for (int n = 0; n < 4; n++)
#pragma unroll
      for (int j = 0; j < 4; j++) {
        int row = wrow * 64 + m * 16 + l4 * 4 + j;
        int col = wcol * 64 + n * 16 + l15;
        *(f16*)(smem + row * 264 + col * 2) = (f16)gelu_exact(acc[m][n][j] + bias[n]);
      }
  __syncthreads();
#pragma unroll
  for (int p = 0; p < 8; ++p) {
    int idx = tid + p * 256;
    int row = idx >> 4, cc = idx & 15;
    if (row < nrows)
      *(float4*)(H + (size_t)(row0 + row) * FFN + n0 + cc * 8) =
          *(const float4*)(smem + row * 264 + cc * 16);
  }
}

// ============ GEMM2: out[tok] += w * (H @ W_out + b_out) ==================
// same structure; K=4096; n-fast decode (A tile reused by 8 blocks per XCD).
__global__ __launch_bounds__(256, 3) void gemm2_k(
    const f16* __restrict__ H, const f16* __restrict__ Wt,
    const float* __restrict__ b_out, float* __restrict__ out,
    const int* __restrict__ meta) {
  int xcd = blockIdx.x & 7, bidx = blockIdx.x >> 3;
  int wg = xcd * (gridDim.x >> 3) + bidx;
  int tm = wg >> 3;            // slow
  int n0 = (wg & 7) * 128;     // fast: A panel reused across 8 blocks
  int e = (meta + 256)[tm];
  if (e < 0) return;
  int row0 = (meta + 512)[tm];
  int nrows = (meta + 768)[tm];
  const int* row_tok = meta + 1024 + 2 * NSLOT;
  const float* row_w = (const float*)(meta + 1024 + 3 * NSLOT);

  __shared__ __align__(16) char smem[32768];

  int tid = threadIdx.x, lane = tid & 63, wid = tid >> 6;
  int wrow = wid >> 1, wcol = wid & 1;
  int l15 = lane & 15, l4 = lane >> 4;

  u32 aoffs[4], boffs[4];
#pragma unroll
  for (int p = 0; p < 4; p++) {
    int L = tid + p * 256;
    int row = L >> 3, ch = L & 7;
    int cs = ch ^ (row & 7);
    aoffs[p] = (u32)((u32)min(row0 + row, NSLOT - 1) * (FFN * 2) + cs * 16);
    boffs[p] = (u32)((u32)(e * DMODEL + n0 + row) * (FFN * 2) + cs * 16);
  }
  const char* gA = (const char*)H;
  const char* gB = (const char*)Wt;

  f32x4 acc[4][4];
#pragma unroll
  for (int m = 0; m < 4; m++)
#pragma unroll
    for (int n = 0; n < 4; n++) acc[m][n] = (f32x4)0.f;

  const int NT = FFN / 64;  // 64
  for (int kt = 0; kt < NT; ++kt) {
#pragma unroll
    for (int p = 0; p < 4; p++) {
      gll16(gA + aoffs[p], smem + (tid + p * 256) * 16);
      gll16(gB + boffs[p], smem + 16384 + (tid + p * 256) * 16);
      aoffs[p] += 128; boffs[p] += 128;
    }
    __syncthreads();
#pragma unroll
    for (int s = 0; s < 2; s++) {
      int swz = ((s * 4 + l4) ^ (l15 & 7)) << 4;
      const char* pA = smem + (wrow * 64 + l15) * 128 + swz;
      const char* pB = smem + 16384 + (wcol * 64 + l15) * 128 + swz;
      half8 a[4], b[4];
#pragma unroll
      for (int i = 0; i < 4; i++) a[i] = *(const half8*)(pA + i * 2048);
#pragma unroll
      for (int j = 0; j < 4; j++) b[j] = *(const half8*)(pB + j * 2048);
#pragma unroll
      for (int i = 0; i < 4; i++)
#pragma unroll
        for (int j = 0; j < 4; j++)
          acc[i][j] = __builtin_amdgcn_mfma_f32_16x16x32_f16(a[i], b[j], acc[i][j], 0, 0, 0);
    }
    __syncthreads();
  }

  float bias[4];
#pragma unroll
  for (int n = 0; n < 4; n++) bias[n] = b_out[e * DMODEL + n0 + wcol * 64 + n * 16 + l15];
#pragma unroll
  for (int m = 0; m < 4; m++)
#pragma unroll
    for (int j = 0; j < 4; j++) {
      int r = wrow * 64 + m * 16 + l4 * 4 + j;
      if (r < nrows) {
        int rg = row0 + r;
        int tok = row_tok[rg];
        float w = row_w[rg];
#pragma unroll
        for (int n = 0; n < 4; n++)
          atomicAdd(out + (size_t)tok * DMODEL + n0 + wcol * 64 + n * 16 + l15,
                    w * (acc[m][n][j] + bias[n]));
      }
    }
}

// ---------------- fallback (small workspace) -------------------------------
__global__ __launch_bounds__(256) void naive_k(
    const float* __restrict__ x, const float* __restrict__ W_in,
    const float* __restrict__ b_in, const float* __restrict__ W_out,
    const float* __restrict__ b_out, const int* __restrict__ sel_e,
    const float* __restrict__ sel_w, float* __restrict__ out) {
  int s = blockIdx.x;
  int t = s >> 1;
  int e = sel_e[s];
  float w = sel_w[s];
  __shared__ float xs[DMODEL];
  __shared__ float hs[FFN];
  int tid = threadIdx.x;
  for (int d = tid; d < DMODEL; d += 256) xs[d] = x[(size_t)t * DMODEL + d];
  __syncthreads();
  for (int f = tid; f < FFN; f += 256) {
    float a = b_in[e * FFN + f];
    const float* wp = W_in + (size_t)e * DMODEL * FFN + f;
    for (int d = 0; d < DMODEL; d++) a += xs[d] * wp[(size_t)d * FFN];
    hs[f] = gelu_exact(a);
  }
  __syncthreads();
  for (int d = tid; d < DMODEL; d += 256) {
    float a = b_out[e * DMODEL + d];
    const float* wp = W_out + (size_t)e * FFN * DMODEL + d;
    for (int f = 0; f < FFN; f++) a += hs[f] * wp[(size_t)f * DMODEL];
    atomicAdd(&out[(size_t)t * DMODEL + d], w * a);
  }
}

extern "C" void kernel_launch(void* const* d_in, const int* in_sizes, int n_in,
                              void* d_out, int out_size, void* d_ws, size_t ws_size,
                              hipStream_t stream) {
  const float* residual = (const float*)d_in[0];
  const float* W_router = (const float*)d_in[1];
  const float* W_in = (const float*)d_in[2];
  const float* b_in = (const float*)d_in[3];
  const float* W_out = (const float*)d_in[4];
  const float* b_out = (const float*)d_in[5];
  float* out = (float*)d_out;

  char* ws = (char*)d_ws;
  int* meta = (int*)ws;
  size_t off = (size_t)1 << 20;
  f16* Xh = (f16*)(ws + off); off += (size_t)T_TOK * DMODEL * 2;       // 16 MB
  f16* Wih = (f16*)(ws + off); off += (size_t)NEXP * DMODEL * FFN * 2; // 64 MB
  f16* Woh = (f16*)(ws + off); off += (size_t)NEXP * DMODEL * FFN * 2; // 64 MB
  f16* H = (f16*)(ws + off); off += (size_t)NSLOT * FFN * 2;           // 128 MB
  off += 65536;                                                        // OOB slack
  bool fast = ws_size >= off;

  int* sel_e = meta + 1024;
  float* sel_w = (float*)(meta + 1024 + NSLOT);
  int* row_tok = meta + 1024 + 2 * NSLOT;
  float* row_w = (float*)(meta + 1024 + 3 * NSLOT);

  hipMemsetAsync(meta, 0, 4096, stream);
  hipMemsetAsync(d_out, 0, (size_t)out_size * sizeof(float), stream);

  router_k<<<T_TOK / 4, 256, 0, stream>>>(residual, W_router, sel_e, sel_w, meta, Xh);

  if (fast) {
    transq_k<<<dim3(FFN / 64, DMODEL / 64, NEXP), 256, 0, stream>>>(W_in, Wih, DMODEL, FFN);
    transq_k<<<dim3(DMODEL / 64, FFN / 64, NEXP), 256, 0, stream>>>(W_out, Woh, FFN, DMODEL);
    sched_k<<<1, 1, 0, stream>>>(meta);
    scatter_k<<<NSLOT / 256, 256, 0, stream>>>(sel_e, sel_w, meta + 128, meta + 64,
                                               row_tok, row_w);
    gemm1_k<<<MAXT * 32, 256, 0, stream>>>(Xh, Wih, b_in, H, meta);
    gemm2_k<<<MAXT * 8, 256, 0, stream>>>(H, Woh, b_out, out, meta);
  } else {
    naive_k<<<NSLOT, 256, 0, stream>>>(residual, W_in, b_in, W_out, b_out,
                                       sel_e, sel_w, out);
  }
}